// Round 16
// baseline (119.590 us; speedup 1.0000x reference)
//
#include <hip/hip_runtime.h>
#include <hip/hip_bf16.h>

#define NROWS 32768
#define HH 128
#define ENTN 50000
#define PEBLKS 1563

typedef _Float16 f16x8 __attribute__((ext_vector_type(8)));
typedef __fp16 fp16x2 __attribute__((ext_vector_type(2)));
typedef float f32x4 __attribute__((ext_vector_type(4)));

// ws byte offsets
#define OFF_PEB 0                       // u32 [50000][128] packed {f16 K*m | f16 K*g} per colpair (25.6 MB)
#define OFF_WF  25600000                // f16 [16jb][4kt][64][8] acc-weight frags, j-interleaved, raw
#define OFF_PO  (OFF_WF + 65536)        // f32 [5][260] {m,g,m,g} per colpair, PRE-SCALED

#define KM 2.8853901f
#define KG (-1.4426950f)
#define RSTR 272                        // acc LDS row stride (256 + 16 pad; 16B-aligned)
#define HALF (32 * RSTR)

#if defined(__has_builtin)
#if __has_builtin(__builtin_amdgcn_exp2f)
#define FEXP2(x) __builtin_amdgcn_exp2f(x)
#endif
#endif
#ifndef FEXP2
__device__ __forceinline__ float __fexp2_asm(float x) {
    float r; asm("v_exp_f32 %0, %1" : "=v"(r) : "v"(x)); return r;
}
#define FEXP2(x) __fexp2_asm(x)
#endif

__device__ __forceinline__ unsigned pk2(float a, float b) {
    fp16x2 h = __builtin_amdgcn_cvt_pkrtz(a, b);
    unsigned u; __builtin_memcpy(&u, &h, 4); return u;
}
__device__ __forceinline__ float h2f(unsigned short s) {
    _Float16 h; __builtin_memcpy(&h, &s, 2); return (float)h;
}

// ---------------- merged pe + prep: blocks [0,1563) compute PEB; rest do prep ----------------
__global__ __launch_bounds__(256, 4)
void pe_prep_kernel(const float* __restrict__ ent_table,
                    const float* __restrict__ op_table,
                    const float* __restrict__ non_table,
                    const float* __restrict__ Wm, const float* __restrict__ bm,
                    const float* __restrict__ Wg, const float* __restrict__ bg,
                    char* __restrict__ ws, float* __restrict__ out) {
    int blk = blockIdx.x;
    int tid = threadIdx.x;
    if (blk < PEBLKS) {
        // ---- pe: PEB[e] = pack(K * (W_ent @ ent^T)) ----
        unsigned* PEB = (unsigned*)(ws + OFF_PEB);
        int w = tid >> 6, l = tid & 63, lr = l & 15, lg = (l >> 4) & 3;
        int e0 = blk * 32;

        // build ent-path weight frags from Wm/Wg (L2-hot)
        f16x8 WB[4][4];
        #pragma unroll
        for (int u = 0; u < 4; ++u) {
            int j = (4 * w + u) * 16 + lr;
            int c = j >> 1, p = j & 1;
            const float* Wrow = (p ? Wg : Wm) + (size_t)c * 384 + 128;
            #pragma unroll
            for (int kt = 0; kt < 4; ++kt) {
                const float4* s = (const float4*)(Wrow + kt * 32 + lg * 8);
                float4 a0 = s[0], a1 = s[1];
                unsigned u4[4] = {pk2(a0.x, a0.y), pk2(a0.z, a0.w),
                                  pk2(a1.x, a1.y), pk2(a1.z, a1.w)};
                __builtin_memcpy(&WB[u][kt], u4, 16);
            }
        }

        #pragma unroll
        for (int rt = 0; rt < 2; ++rt) {
            int e = e0 + rt * 16 + lr;
            if (e >= ENTN) e = ENTN - 1;
            const float4* s = (const float4*)(ent_table + (size_t)e * HH + lg * 8);
            float4 v[4][2];
            #pragma unroll
            for (int kt = 0; kt < 4; ++kt) {       // hoisted: 8 independent 16B loads
                v[kt][0] = s[kt * 8];
                v[kt][1] = s[kt * 8 + 1];
            }
            f32x4 C[4];
            #pragma unroll
            for (int u = 0; u < 4; ++u) C[u] = (f32x4){0.f, 0.f, 0.f, 0.f};
            #pragma unroll
            for (int kt = 0; kt < 4; ++kt) {
                unsigned u4[4] = {pk2(v[kt][0].x, v[kt][0].y), pk2(v[kt][0].z, v[kt][0].w),
                                  pk2(v[kt][1].x, v[kt][1].y), pk2(v[kt][1].z, v[kt][1].w)};
                f16x8 A; __builtin_memcpy(&A, u4, 16);
                #pragma unroll
                for (int u = 0; u < 4; ++u)
                    C[u] = __builtin_amdgcn_mfma_f32_16x16x32_f16(WB[u][kt], A, C[u], 0, 0, 0);
            }
            int e2 = e0 + rt * 16 + lr;
            if (e2 < ENTN) {
                #pragma unroll
                for (int u = 0; u < 4; ++u) {
                    uint2 st;
                    st.x = pk2(C[u][0] * KM, C[u][1] * KG);
                    st.y = pk2(C[u][2] * KM, C[u][3] * KG);
                    *(uint2*)(PEB + (size_t)e2 * HH + (4 * w + u) * 8 + 2 * lg) = st;
                }
            }
        }
    } else {
        // ---- prep: WF, PO(pre-scaled), out tail ----
        int idx = (blk - PEBLKS) * 256 + tid;
        if (idx < 32768) {                       // WF: acc-path frags (raw)
            int e = idx;
            int jj = e & 7, l = (e >> 3) & 63, kt = (e >> 9) & 3, jb = e >> 11;
            int j = jb * 16 + (l & 15);
            int c = j >> 1, p = j & 1;
            int k = kt * 32 + (l >> 4) * 8 + jj;
            const float* Wrow = p ? (Wg + (size_t)c * 384) : (Wm + (size_t)c * 384);
            ((_Float16*)(ws + OFF_WF))[e] = (_Float16)Wrow[256 + k];
        } else if (idx < 34048) {                // PO: pre-scaled, colpair-interleaved
            int e = idx - 32768;
            int o = e >> 8, jj = e & 255;
            int c = jj >> 1, p = jj & 1;
            const float* Wrow = p ? (Wg + (size_t)c * 384) : (Wm + (size_t)c * 384);
            float s = p ? bg[c] : bm[c];
            for (int i = 0; i < 128; ++i) s += op_table[o * HH + i] * Wrow[i];
            s *= (p ? KG : KM);
            ((float*)(ws + OFF_PO))[o * 260 + (c >> 1) * 4 + 2 * (c & 1) + p] = s;
        } else if (idx < 34176) {
            int j = idx - 34048;
            out[(size_t)NROWS * HH + j] = non_table[j];
        }
    }
}

// ---------------- fused 17-step chain (v14 verbatim) ----------------
__global__ __launch_bounds__(1024, 8)
void chain_kernel(const float* __restrict__ ent_table,
                  const int* __restrict__ ops_idx,
                  const int* __restrict__ ents_idx,
                  const int* __restrict__ left_idx,
                  const char* __restrict__ ws, float* __restrict__ out) {
    __shared__ char Abuf[2 * HALF];    // [2p][32r][272B]
    __shared__ unsigned eo[32 * 17];   // (e<<9) | o, [r][t]
    __shared__ float po_s[5 * 260];

    const char* PEBc = ws + OFF_PEB;
    const f16x8* WF2p = (const f16x8*)(ws + OFF_WF);
    const float* POg = (const float*)(ws + OFF_PO);

    int tid = threadIdx.x;
    int jb = tid >> 6, l = tid & 63, lr = l & 15, lg = (l >> 4) & 3;
    int row0 = blockIdx.x * 32;
    int c1 = jb * 8 + 2 * lg;

    if (tid < 544) {
        int r = tid / 17, t = tid - r * 17;
        unsigned e, o;
        if (t < 16) {
            e = ents_idx[(row0 + r) * 17 + 15 - t];
            o = ops_idx[(row0 + r) * 16 + 15 - t];
        } else {
            e = left_idx[row0 + r];
            o = 4;
        }
        eo[tid] = (e << 9) | o;
    }
    for (int i = tid; i < 1300; i += 1024) po_s[i] = POg[i];

    f16x8 WH[4];
    #pragma unroll
    for (int kt = 0; kt < 4; ++kt)
        WH[kt] = WF2p[(jb * 4 + kt) * 64 + l];

    {   // acc0 init -> parity 0
        int r = tid >> 5, sub = tid & 31;
        int e = ents_idx[(row0 + r) * 17 + 16];
        float4 v = *(const float4*)(ent_table + (size_t)e * HH + sub * 4);
        uint2 d;
        d.x = pk2(v.x, v.y);
        d.y = pk2(v.z, v.w);
        *(uint2*)(Abuf + r * RSTR + sub * 8) = d;
    }
    __syncthreads();

    int rb = lr * RSTR + lg * 16;            // MFMA B-operand read base
    int wb = lr * RSTR + jb * 16 + 4 * lg;   // acc write base
    const char* pebBase = PEBc + c1 * 4;
    const float* poBase = po_s + (4 * jb + lg) * 4;
    const unsigned* eoB = eo + lr * 17;

    const f32x4 K4 = (f32x4){KM, KG, KM, KG};

    // prologue: gather for t=0
    unsigned va = eoB[0], vb = eoB[272];
    uint2 pea = *(const uint2*)(pebBase + (va & 0xFFFFFE00u));
    uint2 peb = *(const uint2*)(pebBase + (vb & 0xFFFFFE00u));

#define DO_STEP(T, RD, WR, FINAL)                                               \
    {                                                                           \
        uint2 npea, npeb; unsigned nva = 0, nvb = 0;                            \
        if (!(FINAL)) {                                                         \
            nva = eoB[(T) + 1];                                                 \
            nvb = eoB[272 + (T) + 1];                                           \
            npea = *(const uint2*)(pebBase + (nva & 0xFFFFFE00u));              \
            npeb = *(const uint2*)(pebBase + (nvb & 0xFFFFFE00u));              \
        }                                                                       \
        f32x4 poa = *(const f32x4*)(poBase + (va & 7u) * 260);                  \
        f32x4 pob = *(const f32x4*)(poBase + (vb & 7u) * 260);                  \
        f32x4 C0 = (f32x4){0.f, 0.f, 0.f, 0.f};                                 \
        f32x4 C1 = (f32x4){0.f, 0.f, 0.f, 0.f};                                 \
        _Pragma("unroll")                                                       \
        for (int kt = 0; kt < 4; ++kt) {                                        \
            f16x8 A0 = *(const f16x8*)(Abuf + rb + (RD) + kt * 64);             \
            f16x8 A1 = *(const f16x8*)(Abuf + rb + (RD) + 16 * RSTR + kt * 64); \
            C0 = __builtin_amdgcn_mfma_f32_16x16x32_f16(WH[kt], A0, C0, 0, 0, 0); \
            C1 = __builtin_amdgcn_mfma_f32_16x16x32_f16(WH[kt], A1, C1, 0, 0, 0); \
        }                                                                       \
        _Pragma("unroll")                                                       \
        for (int rt = 0; rt < 2; ++rt) {                                        \
            uint2 pe = rt ? peb : pea;                                          \
            f32x4 po = rt ? pob : poa;                                          \
            f32x4 z = rt ? C1 : C0;                                             \
            f32x4 pef;                                                          \
            pef[0] = h2f((unsigned short)pe.x);                                 \
            pef[1] = h2f((unsigned short)(pe.x >> 16));                         \
            pef[2] = h2f((unsigned short)pe.y);                                 \
            pef[3] = h2f((unsigned short)(pe.y >> 16));                         \
            f32x4 s4 = pef + po;                                                \
            f32x4 a = z * K4 + s4;                                              \
            f32x4 ev;                                                           \
            ev[0] = FEXP2(a[0]); ev[1] = FEXP2(a[1]);                           \
            ev[2] = FEXP2(a[2]); ev[3] = FEXP2(a[3]);                           \
            f32x4 p1 = ev + 1.0f;                                               \
            float r1 = (ev[0] - 1.f) * __builtin_amdgcn_rcpf(p1[0] * p1[1]);    \
            float r2 = (ev[2] - 1.f) * __builtin_amdgcn_rcpf(p1[2] * p1[3]);    \
            if (FINAL) {                                                        \
                float2 o2 = make_float2(r1, r2);                                \
                *(float2*)(out + (size_t)(row0 + rt * 16 + lr) * HH + c1) = o2; \
            } else {                                                            \
                *(unsigned*)(Abuf + wb + (WR) + rt * 16 * RSTR) = pk2(r1, r2);  \
            }                                                                   \
        }                                                                       \
        __syncthreads();                                                        \
        if (!(FINAL)) { pea = npea; peb = npeb; va = nva; vb = nvb; }           \
    }

    for (int tb = 0; tb < 8; ++tb) {
        int t0 = 2 * tb;
        DO_STEP(t0, 0, HALF, 0)
        DO_STEP(t0 + 1, HALF, 0, 0)
    }
    DO_STEP(16, 0, HALF, 1)
#undef DO_STEP
}

extern "C" void kernel_launch(void* const* d_in, const int* in_sizes, int n_in,
                              void* d_out, int out_size, void* d_ws, size_t ws_size,
                              hipStream_t stream) {
    const float* ent_table = (const float*)d_in[0];
    const float* op_table  = (const float*)d_in[1];
    const float* non_table = (const float*)d_in[2];
    const float* Wm        = (const float*)d_in[3];
    const float* bm        = (const float*)d_in[4];
    const float* Wg        = (const float*)d_in[5];
    const float* bg        = (const float*)d_in[6];
    const int* ops_idx     = (const int*)d_in[7];
    const int* ents_idx    = (const int*)d_in[8];
    const int* left_idx    = (const int*)d_in[9];
    float* out = (float*)d_out;
    char* ws = (char*)d_ws;

    pe_prep_kernel<<<PEBLKS + 134, 256, 0, stream>>>(ent_table, op_table, non_table,
                                                     Wm, bm, Wg, bg, ws, out);
    chain_kernel<<<NROWS / 32, 1024, 0, stream>>>(ent_table, ops_idx, ents_idx,
                                                  left_idx, ws, out);
}

// Round 18
// 101.724 us; speedup vs baseline: 1.1756x; 1.1756x over previous
//
#include <hip/hip_runtime.h>
#include <hip/hip_bf16.h>
#include <hip/hip_fp16.h>

#define NROWS 32768
#define HH 128
#define ENTN 50000

typedef _Float16 f16x8 __attribute__((ext_vector_type(8)));
typedef __fp16 fp16x2 __attribute__((ext_vector_type(2)));
typedef float f32x4 __attribute__((ext_vector_type(4)));
typedef float f32x16 __attribute__((ext_vector_type(16)));

// ws byte offsets
#define OFF_PEB 0                       // u32 [50000][8jb][2h][4q][2pr] packed {f16 K*m | f16 K*g} (25.6 MB)
#define OFF_EB  25600000                // f16 [50000][128] (12.8 MB)
#define OFF_WF  38400000                // f16 [8jb][8kt][64][8] acc-weight frags, K-scaled (65536 B)
#define OFF_PEF (OFF_WF + 65536)        // f16 [16jb][4kt][64][8] ent-weight frags, raw (65536 B)
#define OFF_POPK (OFF_PEF + 65536)      // u32 [5][8jb][2h][4q][2pr] packed f16 {K*m,K*g} (2560 B)

#define KM 2.8853901f
#define KG (-1.4426950f)
#define RSTR 272                        // acc LDS row stride (256 + 16 pad)
#define HALF (32 * RSTR)                // 8704 B per parity buffer

#if defined(__has_builtin)
#if __has_builtin(__builtin_amdgcn_exp2f)
#define FEXP2(x) __builtin_amdgcn_exp2f(x)
#endif
#endif
#ifndef FEXP2
__device__ __forceinline__ float __fexp2_asm(float x) {
    float r; asm("v_exp_f32 %0, %1" : "=v"(r) : "v"(x)); return r;
}
#define FEXP2(x) __fexp2_asm(x)
#endif

__device__ __forceinline__ unsigned pk2(float a, float b) {
    fp16x2 h = __builtin_amdgcn_cvt_pkrtz(a, b);
    unsigned u; __builtin_memcpy(&u, &h, 4); return u;
}
__device__ __forceinline__ unsigned pk2rtn(float a, float b) {
    _Float16 lo = (_Float16)a, hi = (_Float16)b;
    unsigned short ul, uh;
    __builtin_memcpy(&ul, &lo, 2); __builtin_memcpy(&uh, &hi, 2);
    return (unsigned)ul | ((unsigned)uh << 16);
}

// ---------------- prep: EB, WF(32x32 layout, K-scaled), PEF, POPK, out tail ----------------
__global__ void prep_kernel(const float* __restrict__ ent_table,
                            const float* __restrict__ op_table,
                            const float* __restrict__ non_table,
                            const float* __restrict__ Wm, const float* __restrict__ bm,
                            const float* __restrict__ Wg, const float* __restrict__ bg,
                            char* __restrict__ ws, float* __restrict__ out) {
    int idx = blockIdx.x * blockDim.x + threadIdx.x;
    if (idx < 800000) {                          // EB: ent_table -> f16, 8 elems/thread
        _Float16* EB = (_Float16*)(ws + OFF_EB);
        int base = idx * 8;
        const float4* s = (const float4*)(ent_table + base);
        float4 v0 = s[0], v1 = s[1];
        float xv[8] = {v0.x, v0.y, v0.z, v0.w, v1.x, v1.y, v1.z, v1.w};
        _Float16 h8[8];
        #pragma unroll
        for (int j = 0; j < 8; ++j) h8[j] = (_Float16)xv[j];
        *(f16x8*)(EB + base) = *(f16x8*)h8;
    } else if (idx < 832768) {                   // WF: 32x32 acc-path frags, K-scaled
        int e = idx - 800000;
        int jj = e & 7, l = (e >> 3) & 63, kt = (e >> 9) & 7, jb = e >> 12;
        int j = jb * 32 + (l & 31);
        int c = j >> 1, p = j & 1;
        int k = kt * 16 + (l >> 5) * 8 + jj;
        const float* Wrow = p ? (Wg + (size_t)c * 384) : (Wm + (size_t)c * 384);
        ((_Float16*)(ws + OFF_WF))[e] = (_Float16)(Wrow[256 + k] * (p ? KG : KM));
    } else if (idx < 865536) {                   // PEF: 16x16 ent-path frags (raw)
        int e = idx - 832768;
        int jj = e & 7, l = (e >> 3) & 63, kt = (e >> 9) & 3, jb = e >> 11;
        int j = jb * 16 + (l & 15);
        int c = j >> 1, p = j & 1;
        int k = kt * 32 + (l >> 4) * 8 + jj;
        const float* Wrow = p ? (Wg + (size_t)c * 384) : (Wm + (size_t)c * 384);
        ((_Float16*)(ws + OFF_PEF))[e] = (_Float16)Wrow[128 + k];
    } else if (idx < 866176) {                   // POPK: packed f16 {K*m, K*g} per u32
        int t2 = idx - 865536;
        int pr = t2 & 1, q = (t2 >> 1) & 3, h = (t2 >> 3) & 1, jb = (t2 >> 4) & 7, o = t2 >> 7;
        int j0 = jb * 32 + 8 * q + 4 * h + 2 * pr;  // even -> m col
        int c = j0 >> 1;
        float sm = bm[c], sg = bg[c];
        const float* Wrm = Wm + (size_t)c * 384;
        const float* Wrg = Wg + (size_t)c * 384;
        for (int i = 0; i < 128; ++i) {
            float ov = op_table[o * HH + i];
            sm += ov * Wrm[i];
            sg += ov * Wrg[i];
        }
        ((unsigned*)(ws + OFF_POPK))[t2] = pk2rtn(sm * KM, sg * KG);
    } else if (idx < 866304) {
        int j = idx - 866176;
        out[(size_t)NROWS * HH + j] = non_table[j];
    }
}

// ---------------- PEB = pack(K * (W_ent @ EB^T)), 16x16 transposed MFMA, remapped store ----------------
__global__ __launch_bounds__(256, 4)
void pe_kernel(char* __restrict__ ws) {
    const char* EBc = ws + OFF_EB;
    const f16x8* PEF = (const f16x8*)(ws + OFF_PEF);
    char* PEB = ws + OFF_PEB;
    int tid = threadIdx.x, w = tid >> 6, l = tid & 63, lr = l & 15, lg = (l >> 4) & 3;
    int e0 = blockIdx.x * 32;

    f16x8 WB[4][4];
    #pragma unroll
    for (int u = 0; u < 4; ++u)
        #pragma unroll
        for (int kt = 0; kt < 4; ++kt)
            WB[u][kt] = PEF[((4 * w + u) * 4 + kt) * 64 + l];

    f32x4 C[2][4];
    #pragma unroll
    for (int rt = 0; rt < 2; ++rt)
        #pragma unroll
        for (int u = 0; u < 4; ++u) C[rt][u] = (f32x4){0.f, 0.f, 0.f, 0.f};

    #pragma unroll
    for (int kt = 0; kt < 4; ++kt) {
        #pragma unroll
        for (int rt = 0; rt < 2; ++rt) {
            int e = e0 + rt * 16 + lr;
            if (e >= ENTN) e = ENTN - 1;
            f16x8 A = *(const f16x8*)(EBc + (size_t)e * 256 + kt * 64 + lg * 16);
            #pragma unroll
            for (int u = 0; u < 4; ++u)
                C[rt][u] = __builtin_amdgcn_mfma_f32_16x16x32_f16(WB[u][kt], A, C[rt][u], 0, 0, 0);
        }
    }
    #pragma unroll
    for (int rt = 0; rt < 2; ++rt) {
        int e = e0 + rt * 16 + lr;
        if (e < ENTN) {
            #pragma unroll
            for (int u = 0; u < 4; ++u) {
                int c = (4 * w + u) * 8 + 2 * lg;      // col-pair base (c, c+1)
                int jb2 = c >> 4, rem = c & 15;
                int q = rem >> 2, h2 = (rem >> 1) & 1;
                uint2 st;
                st.x = pk2(C[rt][u][0] * KM, C[rt][u][1] * KG);
                st.y = pk2(C[rt][u][2] * KM, C[rt][u][3] * KG);
                *(uint2*)(PEB + (size_t)e * 512 + jb2 * 64 + h2 * 32 + q * 8) = st;
            }
        }
    }
}

// ---------------- fused 17-step chain: 32x32x16 MFMA, 8 waves, pe/po as C-init ----------------
__global__ __launch_bounds__(512, 4)
void chain_kernel(const float* __restrict__ ent_table,
                  const int* __restrict__ ops_idx,
                  const int* __restrict__ ents_idx,
                  const int* __restrict__ left_idx,
                  const char* __restrict__ ws, float* __restrict__ out) {
    __shared__ char Abuf[2 * HALF];    // [2p][32r][272B]
    __shared__ unsigned eo[17 * 32];   // [t][r]: (e<<9) | o
    __shared__ unsigned popk[640];

    const char* PEBc = ws + OFF_PEB;
    const f16x8* WFp = (const f16x8*)(ws + OFF_WF);
    const unsigned* POPKg = (const unsigned*)(ws + OFF_POPK);

    int tid = threadIdx.x;
    int jb = tid >> 6, l = tid & 63, r = l & 31, h = l >> 5;
    int row0 = blockIdx.x * 32;

    for (int i = tid; i < 544; i += 512) {
        int t = i >> 5, rr = i & 31;
        unsigned e, o;
        if (t < 16) {
            e = ents_idx[(row0 + rr) * 17 + 15 - t];
            o = ops_idx[(row0 + rr) * 16 + 15 - t];
        } else {
            e = left_idx[row0 + rr];
            o = 4;
        }
        eo[i] = (e << 9) | o;
    }
    for (int i = tid; i < 640; i += 512) popk[i] = POPKg[i];

    f16x8 WH[8];
    #pragma unroll
    for (int kt = 0; kt < 8; ++kt)
        WH[kt] = WFp[(jb * 8 + kt) * 64 + l];

    {   // acc0 init -> parity 0
        int rr = tid >> 4, sub = tid & 15;
        int e = ents_idx[(row0 + rr) * 17 + 16];
        const float4* src = (const float4*)(ent_table + (size_t)e * HH + sub * 8);
        float4 v0 = src[0], v1 = src[1];
        uint4 d;
        d.x = pk2(v0.x, v0.y); d.y = pk2(v0.z, v0.w);
        d.z = pk2(v1.x, v1.y); d.w = pk2(v1.z, v1.w);
        *(uint4*)(Abuf + rr * RSTR + sub * 16) = d;
    }
    __syncthreads();

    int rb = r * RSTR + h * 16;              // B-frag read base (+ kt*32)
    int wb = r * RSTR + jb * 32 + h * 4;     // acc write base (+ q*8)
    const char* pebBase = PEBc + jb * 64 + h * 32;
    const char* popkB = (const char*)popk + jb * 64 + h * 32;
    const unsigned* eoB = eo + r;

    // prologue: pe gather for t=0
    unsigned va = eoB[0];
    uint4 pa0 = *(const uint4*)(pebBase + (va & 0xFFFFFE00u));
    uint4 pa1 = *(const uint4*)(pebBase + (va & 0xFFFFFE00u) + 16);

#define DO_STEP(T, RD, WR, FINAL)                                               \
    {                                                                           \
        uint4 npa0, npa1; unsigned nva = 0;                                     \
        if (!(FINAL)) {                                                         \
            nva = eoB[((T) + 1) * 32];                                          \
            npa0 = *(const uint4*)(pebBase + (nva & 0xFFFFFE00u));              \
            npa1 = *(const uint4*)(pebBase + (nva & 0xFFFFFE00u) + 16);         \
        }                                                                       \
        const char* pq = popkB + (va & 7u) * 512;                               \
        uint4 po0 = *(const uint4*)(pq);                                        \
        uint4 po1 = *(const uint4*)(pq + 16);                                   \
        unsigned pe_u[8] = {pa0.x, pa0.y, pa0.z, pa0.w, pa1.x, pa1.y, pa1.z, pa1.w}; \
        unsigned po_u[8] = {po0.x, po0.y, po0.z, po0.w, po1.x, po1.y, po1.z, po1.w}; \
        f32x16 C;                                                               \
        _Pragma("unroll")                                                       \
        for (int q = 0; q < 4; ++q)                                             \
            _Pragma("unroll")                                                   \
            for (int pr = 0; pr < 2; ++pr) {                                    \
                int u = q * 2 + pr;                                             \
                __half2 sa = *(const __half2*)&pe_u[u];                         \
                __half2 sb = *(const __half2*)&po_u[u];                         \
                __half2 s = __hadd2(sa, sb);                                    \
                C[4 * q + 2 * pr] = __low2float(s);                             \
                C[4 * q + 2 * pr + 1] = __high2float(s);                        \
            }                                                                   \
        _Pragma("unroll")                                                       \
        for (int kt = 0; kt < 8; ++kt) {                                        \
            f16x8 A = *(const f16x8*)(Abuf + rb + (RD) + kt * 32);              \
            C = __builtin_amdgcn_mfma_f32_32x32x16_f16(WH[kt], A, C, 0, 0, 0);  \
        }                                                                       \
        _Pragma("unroll")                                                       \
        for (int q = 0; q < 4; ++q) {                                           \
            float ov[2];                                                        \
            _Pragma("unroll")                                                   \
            for (int pr = 0; pr < 2; ++pr) {                                    \
                float m = C[4 * q + 2 * pr];                                    \
                float g = C[4 * q + 2 * pr + 1];                                \
                float em = FEXP2(m), eg = FEXP2(g);                             \
                ov[pr] = (em - 1.f) * __builtin_amdgcn_rcpf((em + 1.f) * (1.f + eg)); \
            }                                                                   \
            if (FINAL) {                                                        \
                *(float2*)(out + (size_t)(row0 + r) * HH + jb * 16 + 4 * q + 2 * h) \
                    = make_float2(ov[0], ov[1]);                                \
            } else {                                                            \
                *(unsigned*)(Abuf + wb + (WR) + q * 8) = pk2(ov[0], ov[1]);     \
            }                                                                   \
        }                                                                       \
        __syncthreads();                                                        \
        if (!(FINAL)) { pa0 = npa0; pa1 = npa1; va = nva; }                     \
    }

    for (int tb = 0; tb < 8; ++tb) {
        int t0 = 2 * tb;
        DO_STEP(t0, 0, HALF, 0)
        DO_STEP(t0 + 1, HALF, 0, 0)
    }
    DO_STEP(16, 0, HALF, 1)
#undef DO_STEP
}

extern "C" void kernel_launch(void* const* d_in, const int* in_sizes, int n_in,
                              void* d_out, int out_size, void* d_ws, size_t ws_size,
                              hipStream_t stream) {
    const float* ent_table = (const float*)d_in[0];
    const float* op_table  = (const float*)d_in[1];
    const float* non_table = (const float*)d_in[2];
    const float* Wm        = (const float*)d_in[3];
    const float* bm        = (const float*)d_in[4];
    const float* Wg        = (const float*)d_in[5];
    const float* bg        = (const float*)d_in[6];
    const int* ops_idx     = (const int*)d_in[7];
    const int* ents_idx    = (const int*)d_in[8];
    const int* left_idx    = (const int*)d_in[9];
    float* out = (float*)d_out;
    char* ws = (char*)d_ws;

    prep_kernel<<<3384, 256, 0, stream>>>(ent_table, op_table, non_table,
                                          Wm, bm, Wg, bg, ws, out);
    pe_kernel<<<1563, 256, 0, stream>>>(ws);
    chain_kernel<<<NROWS / 32, 512, 0, stream>>>(ent_table, ops_idx, ents_idx,
                                                 left_idx, ws, out);
}